// Round 1
// baseline (972.017 us; speedup 1.0000x reference)
//
#include <hip/hip_runtime.h>

// ---------------------------------------------------------------------------
// GFGCN round 3: occupancy-restructured register-direct MFMA GEMMs.
//
// Change vs round 2: S-GEMM was 512 blocks (2 waves/SIMD) with 10 cache-loads
// feeding 16 MFMAs per k-step -> latency-bound (L2-hit ~200cyc, m125/m126).
// Now: 2x2 wave grid per block (wave = 32x64, block = 64x128), 1024 blocks
// at SP=8 -> 4 blocks/CU = 4 waves/SIMD, VGPR ~100 (launch_bounds(256,4)),
// plus an explicit 2-deep fragment pipeline (>=12 loads in flight/wave).
//
// Frag layouts (m89/m91-verified):
//   A-frag : lane holds A[m = l15][k = quad*8 + j]   (16 B contiguous/lane)
//   B-frag : lane holds B[k = quad*8 + j][n = l15]   == Bt[n][k..k+7]
//   C/D    : reg r -> row = quad*4 + r, col = l15    (rows contiguous)
// ---------------------------------------------------------------------------

typedef __attribute__((ext_vector_type(4))) float  f32x4;
typedef __attribute__((ext_vector_type(8))) __bf16 bf16x8;
typedef __attribute__((ext_vector_type(4))) __bf16 bf16x4;

// ---- fp32 -> bf16, vectorized ----
__global__ void cvt_f32_bf16(const float4* __restrict__ in,
                             bf16x4* __restrict__ out, int n4) {
    int i  = blockIdx.x * blockDim.x + threadIdx.x;
    int st = gridDim.x * blockDim.x;
    for (; i < n4; i += st) {
        float4 v = in[i];
        bf16x4 o;
        o[0] = (__bf16)v.x; o[1] = (__bf16)v.y;
        o[2] = (__bf16)v.z; o[3] = (__bf16)v.w;
        out[i] = o;
    }
}

// ---- fp32 W[K][M] -> bf16 Wt[M][K] (tiny matrices) ----
__global__ void cvt_transpose(const float* __restrict__ W,
                              __bf16* __restrict__ Wt, int Kd, int Md) {
    int i = blockIdx.x * blockDim.x + threadIdx.x;
    if (i < Kd * Md) {
        int k = i / Md, m = i % Md;
        Wt[(size_t)m * Kd + k] = (__bf16)W[i];
    }
}

// ---------------------------------------------------------------------------
// Register-direct GEMM. Block = 4 waves in a 2x2 (M,N) grid; wave covers
// (MF*16) rows x (NF*16) cols. BM = 32*MF, BN = 32*NF.
// grid: x = m-tile, y = n-tile, z = K-split.
// OUTMODE 0: fp32 partial, t-layout P[z][col][row] (row contiguous, f32x4)
// OUTMODE 1: bf16 row-major out[row][ldO + col] (scattered 2B, small data)
// ---------------------------------------------------------------------------
template<int MF, int NF, int OUTMODE>
__global__ __launch_bounds__(256, 4)
void gemm_rd(const __bf16* __restrict__ A, const __bf16* __restrict__ Bt,
             void* __restrict__ out, int K, int Kchunk, int Mtot, int Ntot)
{
    const int lane = threadIdx.x & 63;
    const int w    = threadIdx.x >> 6;
    const int wm   = w >> 1;          // 0..1
    const int wn   = w & 1;           // 0..1
    const int l15  = lane & 15;
    const int quad = lane >> 4;

    const int m_base = blockIdx.x * (32 * MF) + wm * (16 * MF);
    const int n_base = blockIdx.y * (32 * NF) + wn * (16 * NF);
    const int kstart = blockIdx.z * Kchunk;

    const __bf16* Ap[MF];
    #pragma unroll
    for (int mf = 0; mf < MF; mf++)
        Ap[mf] = A + (size_t)(m_base + mf * 16 + l15) * K + kstart + quad * 8;
    const __bf16* Bp[NF];
    #pragma unroll
    for (int nf = 0; nf < NF; nf++)
        Bp[nf] = Bt + (size_t)(n_base + nf * 16 + l15) * K + kstart + quad * 8;

    f32x4 acc[MF][NF];
    #pragma unroll
    for (int mf = 0; mf < MF; mf++)
        #pragma unroll
        for (int nf = 0; nf < NF; nf++)
            acc[mf][nf] = (f32x4){0.f, 0.f, 0.f, 0.f};

    // explicit 2-deep pipeline (Kchunk % 64 == 0 for all call sites)
    bf16x8 a0[MF], b0[NF], a1[MF], b1[NF];
    #pragma unroll
    for (int mf = 0; mf < MF; mf++) a0[mf] = *(const bf16x8*)(Ap[mf]);
    #pragma unroll
    for (int nf = 0; nf < NF; nf++) b0[nf] = *(const bf16x8*)(Bp[nf]);

    #pragma unroll 1
    for (int ks = 0; ks < Kchunk; ks += 64) {
        // issue stage-1 loads (ks+32) before stage-0 MFMAs
        #pragma unroll
        for (int mf = 0; mf < MF; mf++) a1[mf] = *(const bf16x8*)(Ap[mf] + ks + 32);
        #pragma unroll
        for (int nf = 0; nf < NF; nf++) b1[nf] = *(const bf16x8*)(Bp[nf] + ks + 32);

        #pragma unroll
        for (int mf = 0; mf < MF; mf++)
            #pragma unroll
            for (int nf = 0; nf < NF; nf++)
                acc[mf][nf] = __builtin_amdgcn_mfma_f32_16x16x32_bf16(
                    a0[mf], b0[nf], acc[mf][nf], 0, 0, 0);

        if (ks + 64 < Kchunk) {
            #pragma unroll
            for (int mf = 0; mf < MF; mf++) a0[mf] = *(const bf16x8*)(Ap[mf] + ks + 64);
            #pragma unroll
            for (int nf = 0; nf < NF; nf++) b0[nf] = *(const bf16x8*)(Bp[nf] + ks + 64);
        }

        #pragma unroll
        for (int mf = 0; mf < MF; mf++)
            #pragma unroll
            for (int nf = 0; nf < NF; nf++)
                acc[mf][nf] = __builtin_amdgcn_mfma_f32_16x16x32_bf16(
                    a1[mf], b1[nf], acc[mf][nf], 0, 0, 0);
    }

    if (OUTMODE == 0) {
        float* P = (float*)out + (size_t)blockIdx.z * Mtot * Ntot;
        #pragma unroll
        for (int mf = 0; mf < MF; mf++) {
            const int rowb = m_base + mf * 16 + quad * 4;
            #pragma unroll
            for (int nf = 0; nf < NF; nf++) {
                const int col = n_base + nf * 16 + l15;
                *(f32x4*)(P + (size_t)col * Mtot + rowb) = acc[mf][nf];
            }
        }
    } else {
        __bf16* O = (__bf16*)out;
        #pragma unroll
        for (int mf = 0; mf < MF; mf++) {
            const int rowb = m_base + mf * 16 + quad * 4;
            #pragma unroll
            for (int nf = 0; nf < NF; nf++) {
                const int col = n_base + nf * 16 + l15;
                #pragma unroll
                for (int r = 0; r < 4; r++)
                    O[(size_t)(rowb + r) * Ntot + col] = (__bf16)acc[mf][nf][r];
            }
        }
    }
}

// ---- sum SP split-partials -> bf16 t-layout Y[f][node] ----
__global__ void reduce_partials(const float* __restrict__ P,
                                __bf16* __restrict__ Y, int total4,
                                int SP, int MN) {
    int i = blockIdx.x * blockDim.x + threadIdx.x;
    if (i >= total4) return;
    size_t base = (size_t)i * 4;
    float4 s = *(const float4*)(P + base);
    for (int sp = 1; sp < SP; sp++) {
        float4 v = *(const float4*)(P + (size_t)sp * MN + base);
        s.x += v.x; s.y += v.y; s.z += v.z; s.w += v.w;
    }
    bf16x4 o; o[0] = (__bf16)s.x; o[1] = (__bf16)s.y;
    o[2] = (__bf16)s.z; o[3] = (__bf16)s.w;
    *(bf16x4*)(Y + base) = o;
}

// ---- combine: out[node][f] = act(h0*Y0 + h1*Y1 + h2*sum(P) + b[f]) ----
// P/Y0t/Y1t are t-layout [f][8192]; output is row-major [node][F].
template<int RELU, int F32OUT>
__global__ void combine_out(const float* __restrict__ P,
                            const __bf16* __restrict__ Y0t,
                            const __bf16* __restrict__ Y1t,
                            const float* __restrict__ h,
                            const float* __restrict__ bias,
                            void* __restrict__ outp,
                            int F, int SP) {
    const int i = blockIdx.x * blockDim.x + threadIdx.x;  // (f, node4)
    const int total = F * 2048;
    if (i >= total) return;
    const int f  = i >> 11;           // / 2048
    const int n4 = i & 2047;
    const size_t base = (size_t)f * 8192 + (size_t)n4 * 4;
    const int MN = F * 8192;

    float4 s = *(const float4*)(P + base);
    for (int sp = 1; sp < SP; sp++) {
        float4 v = *(const float4*)(P + (size_t)sp * MN + base);
        s.x += v.x; s.y += v.y; s.z += v.z; s.w += v.w;
    }
    bf16x4 y0 = *(const bf16x4*)(Y0t + base);
    bf16x4 y1 = *(const bf16x4*)(Y1t + base);
    const float h0 = h[0], h1 = h[1], h2 = h[2], bb = bias[f];

    float v[4] = {s.x, s.y, s.z, s.w};
    #pragma unroll
    for (int r = 0; r < 4; r++) {
        float x = h0 * (float)y0[r] + h1 * (float)y1[r] + h2 * v[r] + bb;
        if (RELU) x = fmaxf(x, 0.0f);
        v[r] = x;
    }
    const int node = n4 * 4;
    if (F32OUT) {
        float* O = (float*)outp;
        #pragma unroll
        for (int r = 0; r < 4; r++) O[(size_t)(node + r) * F + f] = v[r];
    } else {
        __bf16* O = (__bf16*)outp;
        #pragma unroll
        for (int r = 0; r < 4; r++) O[(size_t)(node + r) * F + f] = (__bf16)v[r];
    }
}

extern "C" void kernel_launch(void* const* d_in, const int* in_sizes, int n_in,
                              void* d_out, int out_size, void* d_ws, size_t ws_size,
                              hipStream_t stream) {
    const float* S  = (const float*)d_in[0];
    const float* X  = (const float*)d_in[1];
    const float* W1 = (const float*)d_in[2];
    const float* h1 = (const float*)d_in[3];
    const float* b1 = (const float*)d_in[4];
    const float* W2 = (const float*)d_in[5];
    const float* h2 = (const float*)d_in[6];
    const float* b2 = (const float*)d_in[7];
    const float* W3 = (const float*)d_in[8];
    const float* h3 = (const float*)d_in[9];
    const float* b3 = (const float*)d_in[10];
    float* out = (float*)d_out;

    const int Nn = 8192, IN = 512, HID = 128, OUT = 64;

    char* ws = (char*)d_ws;
    size_t off = 0;
    auto carve = [&](size_t bytes) -> void* {
        void* p = ws + off;
        off += (bytes + 255) & ~(size_t)255;
        return p;
    };
    __bf16* Sb  = (__bf16*)carve((size_t)Nn * Nn  * 2);   // 134.2 MB
    __bf16* Xb  = (__bf16*)carve((size_t)Nn * IN  * 2);   // 8.4 MB
    __bf16* W1t = (__bf16*)carve((size_t)IN  * HID * 2);
    __bf16* W2t = (__bf16*)carve((size_t)HID * HID * 2);
    __bf16* W3t = (__bf16*)carve((size_t)HID * OUT * 2);
    __bf16* Y0t = (__bf16*)carve((size_t)HID * Nn * 2);   // [F][8192]
    __bf16* Y1t = (__bf16*)carve((size_t)HID * Nn * 2);
    __bf16* Act = (__bf16*)carve((size_t)Nn * HID * 2);   // [node][F]
    size_t  base = off;

    // split-K factor adaptive to remaining workspace (4 MB per split @F=128)
    const size_t per_split = (size_t)HID * Nn * 4;
    int SP = 1;
    while (SP < 8 && base + (size_t)(SP * 2) * per_split <= ws_size) SP *= 2;
    float* P = (float*)carve((size_t)SP * per_split);
    const int KCH = Nn / SP;

    // ---- converts ----
    {
        int n4 = Nn * Nn / 4;
        cvt_f32_bf16<<<dim3((n4 + 255) / 256), dim3(256), 0, stream>>>(
            (const float4*)S, (bf16x4*)Sb, n4);
        n4 = Nn * IN / 4;
        cvt_f32_bf16<<<dim3((n4 + 255) / 256), dim3(256), 0, stream>>>(
            (const float4*)X, (bf16x4*)Xb, n4);
    }
    cvt_transpose<<<dim3((IN * HID + 255) / 256), dim3(256), 0, stream>>>(W1, W1t, IN, HID);
    cvt_transpose<<<dim3((HID * HID + 255) / 256), dim3(256), 0, stream>>>(W2, W2t, HID, HID);
    cvt_transpose<<<dim3((HID * OUT + 255) / 256), dim3(256), 0, stream>>>(W3, W3t, HID, OUT);

    // S-GEMM: partials P[s][f][node];  A=Sb ldA=8192, B=Yt ldB=8192
    // block = 64 rows x (32*NF) cols; grid = (8192/64, 1, SP)
    auto sgemm = [&](const __bf16* Bt, int F) {
        if (F == 128)
            gemm_rd<2, 4, 0><<<dim3(Nn / 64, 1, SP), dim3(256), 0, stream>>>(
                Sb, Bt, P, Nn, KCH, Nn, F);
        else
            gemm_rd<2, 2, 0><<<dim3(Nn / 64, 1, SP), dim3(256), 0, stream>>>(
                Sb, Bt, P, Nn, KCH, Nn, F);
    };
    auto reduceY = [&](__bf16* Y, int F) {
        int t4 = F * 2048;
        reduce_partials<<<dim3((t4 + 255) / 256), dim3(256), 0, stream>>>(
            P, Y, t4, SP, F * Nn);
    };

    // ---- layer 1 ----
    // Y0t = W1t @ Xb   (M=128, N=8192, K=512); block 64x128 -> grid (2, 64)
    gemm_rd<2, 4, 1><<<dim3(HID / 64, Nn / 128, 1), dim3(256), 0, stream>>>(
        W1t, Xb, Y0t, IN, IN, HID, Nn);
    sgemm(Y0t, HID);                       // P = split-partials of S@Y0
    reduceY(Y1t, HID);                     // Y1t = S@Y0
    sgemm(Y1t, HID);                       // P = split-partials of S@Y1
    combine_out<1, 0><<<dim3(HID * 2048 / 256), dim3(256), 0, stream>>>(
        P, Y0t, Y1t, h1, b1, Act, HID, SP);

    // ---- layer 2 ----
    gemm_rd<2, 4, 1><<<dim3(HID / 64, Nn / 128, 1), dim3(256), 0, stream>>>(
        W2t, Act, Y0t, HID, HID, HID, Nn);
    sgemm(Y0t, HID);
    reduceY(Y1t, HID);
    sgemm(Y1t, HID);
    combine_out<1, 0><<<dim3(HID * 2048 / 256), dim3(256), 0, stream>>>(
        P, Y0t, Y1t, h2, b2, Act, HID, SP);

    // ---- layer 3 (F=64, fp32 out, no relu); W3t is M=64 -> grid (1, 64) ----
    gemm_rd<2, 4, 1><<<dim3(OUT / 64, Nn / 128, 1), dim3(256), 0, stream>>>(
        W3t, Act, Y0t, HID, HID, OUT, Nn);
    sgemm(Y0t, OUT);
    reduceY(Y1t, OUT);
    sgemm(Y1t, OUT);
    combine_out<0, 1><<<dim3(OUT * 2048 / 256), dim3(256), 0, stream>>>(
        P, Y0t, Y1t, h3, b3, out, OUT, SP);

    (void)in_sizes; (void)n_in; (void)out_size;
}

// Round 2
// 702.197 us; speedup vs baseline: 1.3843x; 1.3843x over previous
//
#include <hip/hip_runtime.h>

// ---------------------------------------------------------------------------
// GFGCN round 4: S-GEMM via global_load_lds double-buffered LDS staging
// (m97 structure); W-GEMMs / converts / reduce / combine reverted verbatim
// to the round-2 (892us) code for clean attribution.
//
// S-GEMM theory: M=8192,N=128,K=8192 -> 128 FLOP/byte of S -> HBM-bound,
// floor 21us (134MB @6.3TB/s). Register-direct version was latency-bound
// (~12 loads max in flight). global_load_lds gives a 16KB async tile in
// flight per block per k-step with no VGPR cost.
//
// Frag layouts (m89/m91-verified):
//   A-frag : lane holds A[m = l15][k = quad*8 + j]
//   B-frag : lane holds B[k = quad*8 + j][n = l15]  == Bt[n][k..k+7]
//   C/D    : reg r -> row = quad*4 + r, col = l15
// ---------------------------------------------------------------------------

typedef __attribute__((ext_vector_type(4))) float  f32x4;
typedef __attribute__((ext_vector_type(8))) __bf16 bf16x8;
typedef __attribute__((ext_vector_type(4))) __bf16 bf16x4;

__device__ __forceinline__ void gload_lds16(const __bf16* g, __bf16* l) {
    __builtin_amdgcn_global_load_lds(
        (const __attribute__((address_space(1))) void*)g,
        (__attribute__((address_space(3))) void*)l, 16, 0, 0);
}

// ---- fp32 -> bf16, vectorized ----
__global__ void cvt_f32_bf16(const float4* __restrict__ in,
                             bf16x4* __restrict__ out, int n4) {
    int i  = blockIdx.x * blockDim.x + threadIdx.x;
    int st = gridDim.x * blockDim.x;
    for (; i < n4; i += st) {
        float4 v = in[i];
        bf16x4 o;
        o[0] = (__bf16)v.x; o[1] = (__bf16)v.y;
        o[2] = (__bf16)v.z; o[3] = (__bf16)v.w;
        out[i] = o;
    }
}

// ---- fp32 W[K][M] -> bf16 Wt[M][K] (tiny matrices) ----
__global__ void cvt_transpose(const float* __restrict__ W,
                              __bf16* __restrict__ Wt, int Kd, int Md) {
    int i = blockIdx.x * blockDim.x + threadIdx.x;
    if (i < Kd * Md) {
        int k = i / Md, m = i % Md;
        Wt[(size_t)m * Kd + k] = (__bf16)W[i];
    }
}

// ---------------------------------------------------------------------------
// Round-2 register-direct GEMM (verbatim) — now used only for W-GEMMs.
// Block = 4 waves stacked in M; wave covers (MF*16) rows x (NF*16) cols.
// ---------------------------------------------------------------------------
template<int MF, int NF, int OUTMODE>
__global__ __launch_bounds__(256)
void gemm_rd(const __bf16* __restrict__ A, const __bf16* __restrict__ Bt,
             void* __restrict__ out, int K, int Kchunk, int Mtot, int Ntot)
{
    const int lane = threadIdx.x & 63;
    const int w    = threadIdx.x >> 6;
    const int l15  = lane & 15;
    const int quad = lane >> 4;

    const int m_base = blockIdx.x * (64 * MF) + w * (16 * MF);
    const int n_base = blockIdx.y * (16 * NF);
    const int kstart = blockIdx.z * Kchunk;

    const __bf16* Ap[MF];
    #pragma unroll
    for (int mf = 0; mf < MF; mf++)
        Ap[mf] = A + (size_t)(m_base + mf * 16 + l15) * K + kstart + quad * 8;
    const __bf16* Bp[NF];
    #pragma unroll
    for (int nf = 0; nf < NF; nf++)
        Bp[nf] = Bt + (size_t)(n_base + nf * 16 + l15) * K + kstart + quad * 8;

    f32x4 acc[MF][NF];
    #pragma unroll
    for (int mf = 0; mf < MF; mf++)
        #pragma unroll
        for (int nf = 0; nf < NF; nf++)
            acc[mf][nf] = (f32x4){0.f, 0.f, 0.f, 0.f};

    #pragma unroll 2
    for (int ks = 0; ks < Kchunk; ks += 32) {
        bf16x8 a[MF], b[NF];
        #pragma unroll
        for (int mf = 0; mf < MF; mf++) a[mf] = *(const bf16x8*)(Ap[mf] + ks);
        #pragma unroll
        for (int nf = 0; nf < NF; nf++) b[nf] = *(const bf16x8*)(Bp[nf] + ks);
        #pragma unroll
        for (int mf = 0; mf < MF; mf++)
            #pragma unroll
            for (int nf = 0; nf < NF; nf++)
                acc[mf][nf] = __builtin_amdgcn_mfma_f32_16x16x32_bf16(
                    a[mf], b[nf], acc[mf][nf], 0, 0, 0);
    }

    if (OUTMODE == 0) {
        float* P = (float*)out + (size_t)blockIdx.z * Mtot * Ntot;
        #pragma unroll
        for (int mf = 0; mf < MF; mf++) {
            const int rowb = m_base + mf * 16 + quad * 4;
            #pragma unroll
            for (int nf = 0; nf < NF; nf++) {
                const int col = n_base + nf * 16 + l15;
                *(f32x4*)(P + (size_t)col * Mtot + rowb) = acc[mf][nf];
            }
        }
    } else {
        __bf16* O = (__bf16*)out;
        #pragma unroll
        for (int mf = 0; mf < MF; mf++) {
            const int rowb = m_base + mf * 16 + quad * 4;
            #pragma unroll
            for (int nf = 0; nf < NF; nf++) {
                const int col = n_base + nf * 16 + l15;
                #pragma unroll
                for (int r = 0; r < 4; r++)
                    O[(size_t)(rowb + r) * Ntot + col] = (__bf16)acc[mf][nf][r];
            }
        }
    }
}

// ---------------------------------------------------------------------------
// NEW: LDS-staged S-GEMM (m97 2-phase structure).
// C[8192][BN] = S @ Y;  A = Sb row-major ldA=8192, B = Yt[n][8192].
// BM=128, BN=16*NF (covers all of N: grid.y implicit 1), BK=32.
// 4 waves stacked in M, each wave 32 rows x BN cols (MF=2).
// Double-buffered LDS A+B tiles filled by global_load_lds width=16.
// LDS dest is linear (wave-uniform base + lane*16) per m104 constraint.
// Output: fp32 partials, t-layout P[z][col][row], rows contiguous (f32x4).
// ---------------------------------------------------------------------------
template<int NF>
__global__ __launch_bounds__(256)
void sgemm_lds(const __bf16* __restrict__ A, const __bf16* __restrict__ Bt,
               float* __restrict__ P, int K, int Kchunk, int Mtot, int Ntot)
{
    __shared__ __bf16 Asm[2][128 * 32];       // [buf][m][k] linear, 8KB each
    __shared__ __bf16 Bsm[2][NF * 16 * 32];   // [buf][n][k] linear

    const int t    = threadIdx.x;             // 0..255
    const int lane = t & 63;
    const int w    = t >> 6;                  // wave 0..3
    const int l15  = lane & 15;
    const int quad = lane >> 4;

    const int m_block = blockIdx.x * 128;
    const int kstart  = blockIdx.z * Kchunk;

    // staging source: thread t covers row (t>>2), k-offset (t&3)*8 (16B)
    const __bf16* gA = A  + (size_t)(m_block + (t >> 2)) * K + kstart + (t & 3) * 8;
    const __bf16* gB = Bt + (size_t)(t >> 2) * K + kstart + (t & 3) * 8;

    f32x4 acc[2][NF];
    #pragma unroll
    for (int mf = 0; mf < 2; mf++)
        #pragma unroll
        for (int nf = 0; nf < NF; nf++)
            acc[mf][nf] = (f32x4){0.f, 0.f, 0.f, 0.f};

    auto stage = [&](int buf, int ks) {
        // A tile: 128 rows x 32 k = 8KB = 2 x (256 thr x 16B)
        gload_lds16(gA + ks,                   &Asm[buf][t * 8]);
        gload_lds16(gA + (size_t)64 * K + ks,  &Asm[buf][2048 + t * 8]);
        // B tile: NF*16 rows x 32 k
        gload_lds16(gB + ks,                   &Bsm[buf][t * 8]);
        if (NF == 8)
            gload_lds16(gB + (size_t)64 * K + ks, &Bsm[buf][2048 + t * 8]);
    };

    stage(0, 0);
    __syncthreads();   // vmcnt(0) drain + barrier: buf0 ready

    int buf = 0;
    for (int ks = 0; ; ) {
        const int nks = ks + 32;
        if (nks < Kchunk) stage(buf ^ 1, nks);   // async, overlaps compute

        bf16x8 a0, a1, b[NF];
        const int arow = w * 32 + l15;
        a0 = *(const bf16x8*)&Asm[buf][(arow)      * 32 + quad * 8];
        a1 = *(const bf16x8*)&Asm[buf][(arow + 16) * 32 + quad * 8];
        #pragma unroll
        for (int nf = 0; nf < NF; nf++)
            b[nf] = *(const bf16x8*)&Bsm[buf][(nf * 16 + l15) * 32 + quad * 8];

        #pragma unroll
        for (int nf = 0; nf < NF; nf++)
            acc[0][nf] = __builtin_amdgcn_mfma_f32_16x16x32_bf16(a0, b[nf], acc[0][nf], 0, 0, 0);
        #pragma unroll
        for (int nf = 0; nf < NF; nf++)
            acc[1][nf] = __builtin_amdgcn_mfma_f32_16x16x32_bf16(a1, b[nf], acc[1][nf], 0, 0, 0);

        ks = nks;
        if (ks >= Kchunk) break;
        __syncthreads();   // stage(buf^1) complete + all waves done reading buf
        buf ^= 1;
    }

    float* Pz = P + (size_t)blockIdx.z * Mtot * Ntot;
    #pragma unroll
    for (int mf = 0; mf < 2; mf++) {
        const int rowb = m_block + w * 32 + mf * 16 + quad * 4;
        #pragma unroll
        for (int nf = 0; nf < NF; nf++) {
            const int col = nf * 16 + l15;
            *(f32x4*)(Pz + (size_t)col * Mtot + rowb) = acc[mf][nf];
        }
    }
    (void)Ntot;
}

// ---- sum SP split-partials -> bf16 t-layout Y[f][node] ----
__global__ void reduce_partials(const float* __restrict__ P,
                                __bf16* __restrict__ Y, int total4,
                                int SP, int MN) {
    int i = blockIdx.x * blockDim.x + threadIdx.x;
    if (i >= total4) return;
    size_t base = (size_t)i * 4;
    float4 s = *(const float4*)(P + base);
    for (int sp = 1; sp < SP; sp++) {
        float4 v = *(const float4*)(P + (size_t)sp * MN + base);
        s.x += v.x; s.y += v.y; s.z += v.z; s.w += v.w;
    }
    bf16x4 o; o[0] = (__bf16)s.x; o[1] = (__bf16)s.y;
    o[2] = (__bf16)s.z; o[3] = (__bf16)s.w;
    *(bf16x4*)(Y + base) = o;
}

// ---- combine: out[node][f] = act(h0*Y0 + h1*Y1 + h2*sum(P) + b[f]) ----
template<int RELU, int F32OUT>
__global__ void combine_out(const float* __restrict__ P,
                            const __bf16* __restrict__ Y0t,
                            const __bf16* __restrict__ Y1t,
                            const float* __restrict__ h,
                            const float* __restrict__ bias,
                            void* __restrict__ outp,
                            int F, int SP) {
    const int i = blockIdx.x * blockDim.x + threadIdx.x;  // (f, node4)
    const int total = F * 2048;
    if (i >= total) return;
    const int f  = i >> 11;           // / 2048
    const int n4 = i & 2047;
    const size_t base = (size_t)f * 8192 + (size_t)n4 * 4;
    const int MN = F * 8192;

    float4 s = *(const float4*)(P + base);
    for (int sp = 1; sp < SP; sp++) {
        float4 v = *(const float4*)(P + (size_t)sp * MN + base);
        s.x += v.x; s.y += v.y; s.z += v.z; s.w += v.w;
    }
    bf16x4 y0 = *(const bf16x4*)(Y0t + base);
    bf16x4 y1 = *(const bf16x4*)(Y1t + base);
    const float h0 = h[0], h1 = h[1], h2 = h[2], bb = bias[f];

    float v[4] = {s.x, s.y, s.z, s.w};
    #pragma unroll
    for (int r = 0; r < 4; r++) {
        float x = h0 * (float)y0[r] + h1 * (float)y1[r] + h2 * v[r] + bb;
        if (RELU) x = fmaxf(x, 0.0f);
        v[r] = x;
    }
    const int node = n4 * 4;
    if (F32OUT) {
        float* O = (float*)outp;
        #pragma unroll
        for (int r = 0; r < 4; r++) O[(size_t)(node + r) * F + f] = v[r];
    } else {
        __bf16* O = (__bf16*)outp;
        #pragma unroll
        for (int r = 0; r < 4; r++) O[(size_t)(node + r) * F + f] = (__bf16)v[r];
    }
}

extern "C" void kernel_launch(void* const* d_in, const int* in_sizes, int n_in,
                              void* d_out, int out_size, void* d_ws, size_t ws_size,
                              hipStream_t stream) {
    const float* S  = (const float*)d_in[0];
    const float* X  = (const float*)d_in[1];
    const float* W1 = (const float*)d_in[2];
    const float* h1 = (const float*)d_in[3];
    const float* b1 = (const float*)d_in[4];
    const float* W2 = (const float*)d_in[5];
    const float* h2 = (const float*)d_in[6];
    const float* b2 = (const float*)d_in[7];
    const float* W3 = (const float*)d_in[8];
    const float* h3 = (const float*)d_in[9];
    const float* b3 = (const float*)d_in[10];
    float* out = (float*)d_out;

    const int Nn = 8192, IN = 512, HID = 128, OUT = 64;

    char* ws = (char*)d_ws;
    size_t off = 0;
    auto carve = [&](size_t bytes) -> void* {
        void* p = ws + off;
        off += (bytes + 255) & ~(size_t)255;
        return p;
    };
    __bf16* Sb  = (__bf16*)carve((size_t)Nn * Nn  * 2);   // 134.2 MB
    __bf16* Xb  = (__bf16*)carve((size_t)Nn * IN  * 2);   // 8.4 MB
    __bf16* W1t = (__bf16*)carve((size_t)IN  * HID * 2);
    __bf16* W2t = (__bf16*)carve((size_t)HID * HID * 2);
    __bf16* W3t = (__bf16*)carve((size_t)HID * OUT * 2);
    __bf16* Y0t = (__bf16*)carve((size_t)HID * Nn * 2);   // [F][8192]
    __bf16* Y1t = (__bf16*)carve((size_t)HID * Nn * 2);
    __bf16* Act = (__bf16*)carve((size_t)Nn * HID * 2);   // [node][F]
    size_t  base = off;

    // split-K factor adaptive to remaining workspace (4 MB per split @F=128)
    const size_t per_split = (size_t)HID * Nn * 4;
    int SP = 1;
    while (SP < 8 && base + (size_t)(SP * 2) * per_split <= ws_size) SP *= 2;
    float* P = (float*)carve((size_t)SP * per_split);
    const int KCH = Nn / SP;

    // ---- converts ----
    {
        int n4 = Nn * Nn / 4;
        cvt_f32_bf16<<<dim3((n4 + 255) / 256), dim3(256), 0, stream>>>(
            (const float4*)S, (bf16x4*)Sb, n4);
        n4 = Nn * IN / 4;
        cvt_f32_bf16<<<dim3((n4 + 255) / 256), dim3(256), 0, stream>>>(
            (const float4*)X, (bf16x4*)Xb, n4);
    }
    cvt_transpose<<<dim3((IN * HID + 255) / 256), dim3(256), 0, stream>>>(W1, W1t, IN, HID);
    cvt_transpose<<<dim3((HID * HID + 255) / 256), dim3(256), 0, stream>>>(W2, W2t, HID, HID);
    cvt_transpose<<<dim3((HID * OUT + 255) / 256), dim3(256), 0, stream>>>(W3, W3t, HID, OUT);

    // S-GEMM (LDS-staged): partials P[s][f][node]; grid = (8192/128, 1, SP)
    auto sgemm = [&](const __bf16* Bt, int F) {
        if (F == 128)
            sgemm_lds<8><<<dim3(Nn / 128, 1, SP), dim3(256), 0, stream>>>(
                Sb, Bt, P, Nn, KCH, Nn, F);
        else
            sgemm_lds<4><<<dim3(Nn / 128, 1, SP), dim3(256), 0, stream>>>(
                Sb, Bt, P, Nn, KCH, Nn, F);
    };
    auto reduceY = [&](__bf16* Y, int F) {
        int t4 = F * 2048;
        reduce_partials<<<dim3((t4 + 255) / 256), dim3(256), 0, stream>>>(
            P, Y, t4, SP, F * Nn);
    };

    // ---- layer 1 ----
    // Y0t = W1t @ Xb   (M=128, N=8192, K=512)  [round-2 geometry]
    gemm_rd<2, 4, 1><<<dim3(1, Nn / 64, 1), dim3(256), 0, stream>>>(
        W1t, Xb, Y0t, IN, IN, HID, Nn);
    sgemm(Y0t, HID);                       // P = split-partials of S@Y0
    reduceY(Y1t, HID);                     // Y1t = S@Y0
    sgemm(Y1t, HID);                       // P = split-partials of S@Y1
    combine_out<1, 0><<<dim3(HID * 2048 / 256), dim3(256), 0, stream>>>(
        P, Y0t, Y1t, h1, b1, Act, HID, SP);

    // ---- layer 2 ----
    gemm_rd<2, 4, 1><<<dim3(1, Nn / 64, 1), dim3(256), 0, stream>>>(
        W2t, Act, Y0t, HID, HID, HID, Nn);
    sgemm(Y0t, HID);
    reduceY(Y1t, HID);
    sgemm(Y1t, HID);
    combine_out<1, 0><<<dim3(HID * 2048 / 256), dim3(256), 0, stream>>>(
        P, Y0t, Y1t, h2, b2, Act, HID, SP);

    // ---- layer 3 (F=64, fp32 out, no relu) ----
    gemm_rd<1, 4, 1><<<dim3(1, Nn / 64, 1), dim3(256), 0, stream>>>(
        W3t, Act, Y0t, HID, HID, OUT, Nn);
    sgemm(Y0t, OUT);
    reduceY(Y1t, OUT);
    sgemm(Y1t, OUT);
    combine_out<0, 1><<<dim3(OUT * 2048 / 256), dim3(256), 0, stream>>>(
        P, Y0t, Y1t, h3, b3, out, OUT, SP);

    (void)in_sizes; (void)n_in; (void)out_size;
}